// Round 8
// baseline (376.631 us; speedup 1.0000x reference)
//
#include <hip/hip_runtime.h>
#include <math.h>

#ifndef M_PI
#define M_PI 3.14159265358979323846
#endif

#define BB     128
#define TT     16384
#define PP     20
#define NCH    18
#define EMIT   256                 // emitted samples per block
#define HIST   192                 // FIR history (0.946^192 ~ 2e-5)
#define WIN    (HIST + EMIT)       // 448 converted rows per block
#define NQ     7                   // K-chunks of 32: (HIST+32)/32
#define NTAPS  208                 // h[0..207], k_max = 15+192
#define VPITCH 484                 // v row pitch in dwords (>=464, ==4 mod 32)
#define PMP    260                 // pm row pitch in u16
#define SEC    112                 // conversion section rows
#define NSEC   4                   // 4*112 = 448 = WIN
#define NCHUNK (TT / EMIT)         // 64

typedef float  f32x2  __attribute__((ext_vector_type(2)));
typedef float  f32x4v __attribute__((ext_vector_type(4)));
typedef short  bf16x8 __attribute__((ext_vector_type(8)));

// bipolar pair probe indices (LL, LP, RP, RL, Z groups, insertion order)
__constant__ int d_P1[NCH] = {0,4,5,6,  0,1,2,3,  11,15,16,17, 11,12,13,14, 8,9};
__constant__ int d_P2[NCH] = {4,5,6,7,  1,2,3,7,  15,16,17,18, 12,13,14,18, 9,10};

__device__ __forceinline__ uint rne16(float f) {
    uint u = __float_as_uint(f);
    return (u + 0x7fffu + ((u >> 16) & 1u)) >> 16;   // round-nearest-even bf16 bits
}

// 1-thread pre-kernel: h = impulse response of HP->LP cascade, double DF1
__global__ void make_h(float* __restrict__ hout,
                       double b0h, double b1h, double b2h, double a1h, double a2h,
                       double b0l, double b1l, double b2l, double a1l, double a2l)
{
    if (threadIdx.x == 0 && blockIdx.x == 0) {
        double hx1=0, hx2=0, hy1=0, hy2=0, lx1=0, lx2=0, ly1=0, ly2=0;
        for (int t = 0; t < NTAPS; ++t) {
            double u = (t == 0) ? 1.0 : 0.0;
            double hy = b0h*u + b1h*hx1 + b2h*hx2 - a1h*hy1 - a2h*hy2;
            hx2 = hx1; hx1 = u;  hy2 = hy1; hy1 = hy;
            double ly = b0l*hy + b1l*lx1 + b2l*lx2 - a1l*ly1 - a2l*ly2;
            lx2 = lx1; lx1 = hy; ly2 = ly1; ly1 = ly;
            hout[t] = (float)ly;
        }
    }
}

__global__ __launch_bounds__(256) void collate_fir(
    const float* __restrict__ x, const float* __restrict__ msk,
    float* __restrict__ out, const float* __restrict__ hg)
{
    __shared__ uint   vlds[NCH * VPITCH];   // packed (bf16_hi<<16)|bf16_lo of v
    __shared__ ushort pmlds[NCH * PMP];     // pm as bf16 bits, emit region only
    __shared__ f32x2  raw[SEC * PP];        // staged (x, m) interleaved
    __shared__ float  hlds[NTAPS];
    __shared__ uint   plds[NCH];            // p1 | (p2<<8)

    int tid   = threadIdx.x;
    int blk   = blockIdx.x;
    int chunk = blk & (NCHUNK - 1);
    int b     = blk >> 6;
    int t0    = chunk * EMIT;

    // ---- prologue: stage h, probe pairs, zero v slack [WIN, VPITCH) ------
    for (int e = tid; e < NTAPS; e += 256) hlds[e] = hg[e];
    if (tid < NCH) plds[tid] = (uint)d_P1[tid] | ((uint)d_P2[tid] << 8);
    for (int e = tid; e < NCH * (VPITCH - WIN); e += 256) {
        int c = e / (VPITCH - WIN);
        int w = WIN + (e - c * (VPITCH - WIN));
        vlds[c * VPITCH + w] = 0u;
    }
    __syncthreads();

    // ---- conversion: stream raw slab -> v (bf16 hi/lo packed), pm --------
    const float* xb = x   + (size_t)b * TT * PP;
    const float* mb = msk + (size_t)b * TT * PP;
    long base = (long)t0 - HIST;           // may be negative for chunk 0

    for (int s = 0; s < NSEC; ++s) {
        int  w0 = s * SEC;
        long g0 = (base + w0) * PP;        // even
        for (int e2 = tid; e2 < SEC * PP / 2; e2 += 256) {
            long g = g0 + 2 * e2;
            f32x2 u0 = {0.f, 0.f}, u1 = {0.f, 0.f};
            if (g >= 0) {
                u0.x = xb[g];     u0.y = mb[g];
                u1.x = xb[g + 1]; u1.y = mb[g + 1];
            }
            raw[2 * e2]     = u0;
            raw[2 * e2 + 1] = u1;
        }
        __syncthreads();
        for (int e = tid; e < SEC * NCH; e += 256) {
            int r = e / NCH;
            int c = e - r * NCH;
            uint pp = plds[c];
            f32x2 u1 = raw[r * PP + (pp & 0xffu)];
            f32x2 u2 = raw[r * PP + (pp >> 8)];
            float pmv = u1.y * u2.y;
            float v   = (u1.x - u2.x) * pmv;
            uint  vh  = rne16(v);
            float vhf = __uint_as_float(vh << 16);
            uint  vl  = rne16(v - vhf);
            int   w   = w0 + r;
            vlds[c * VPITCH + w] = (vh << 16) | vl;
            if (w >= HIST) pmlds[c * PMP + (w - HIST)] = (ushort)rne16(pmv);
        }
        __syncthreads();
    }

    // ---- emit pm: bf16 -> f32, coalesced f32x4 row stores -----------------
    float* oute = out;
    float* outm = out + (size_t)BB * NCH * TT;
    for (int e = tid; e < NCH * EMIT / 4; e += 256) {     // 1152 quads
        int c  = e >> 6;
        int tq = e & 63;
        uint2 two = *reinterpret_cast<uint2*>(&pmlds[c * PMP + 4 * tq]);
        f32x4v o;
        o.x = __uint_as_float((two.x & 0xffffu) << 16);
        o.y = __uint_as_float(two.x & 0xffff0000u);
        o.z = __uint_as_float((two.y & 0xffffu) << 16);
        o.w = __uint_as_float(two.y & 0xffff0000u);
        *reinterpret_cast<f32x4v*>(outm + ((size_t)b * NCH + c) * TT + t0 + 4 * tq) = o;
    }

    // ---- build A-fragments: Toeplitz h slices, hi/lo bf16 -----------------
    int lane = tid & 63;
    int wid  = tid >> 6;
    int i16  = lane & 15;
    int g    = lane >> 4;

    bf16x8 Ah[NQ], Al[NQ];
#pragma unroll
    for (int q = 0; q < NQ; ++q) {
#pragma unroll
        for (int e = 0; e < 8; ++e) {
            int   k  = i16 + HIST - 32 * q - (g * 8 + e);
            float hv = (k >= 0 && k < NTAPS) ? hlds[k] : 0.f;
            uint  hh = rne16(hv);
            float hf = __uint_as_float(hh << 16);
            uint  hl = rne16(hv - hf);
            Ah[q][e] = (short)hh;
            Al[q][e] = (short)hl;
        }
    }

    // ---- MFMA: 16 main tiles (c=0..15) + 2 packed tiles (c=16,17 x 8 sub) -
    for (int tile = wid; tile < 18; tile += 4) {
        int n = lane & 15;
        int c, Tl;
        if (tile < 16) { c = n;             Tl = tile * 16; }
        else           { c = 16 + (n >> 3); Tl = (tile - 16) * 128 + (n & 7) * 16; }

        f32x4v acc = {0.f, 0.f, 0.f, 0.f};
#pragma unroll
        for (int q = 0; q < NQ; ++q) {
            int off = c * VPITCH + Tl + 32 * q + 8 * g;
            uint4 w0 = *reinterpret_cast<uint4*>(&vlds[off]);
            uint4 w1 = *reinterpret_cast<uint4*>(&vlds[off + 4]);
            uint  u[8] = {w0.x, w0.y, w0.z, w0.w, w1.x, w1.y, w1.z, w1.w};
            bf16x8 Bh, Bl;
#pragma unroll
            for (int e = 0; e < 8; ++e) {
                Bh[e] = (short)(u[e] >> 16);
                Bl[e] = (short)(u[e] & 0xffffu);
            }
            acc = __builtin_amdgcn_mfma_f32_16x16x32_bf16(Ah[q], Bh, acc, 0, 0, 0);
            acc = __builtin_amdgcn_mfma_f32_16x16x32_bf16(Ah[q], Bl, acc, 0, 0, 0);
            acc = __builtin_amdgcn_mfma_f32_16x16x32_bf16(Al[q], Bh, acc, 0, 0, 0);
        }
        // C/D: col = lane&15 (=n), row = g*4 + reg  -> 4 consecutive times
        *reinterpret_cast<f32x4v*>(oute + ((size_t)b * NCH + c) * TT + t0 + Tl + g * 4) = acc;
    }
}

extern "C" void kernel_launch(void* const* d_in, const int* in_sizes, int n_in,
                              void* d_out, int out_size, void* d_ws, size_t ws_size,
                              hipStream_t stream)
{
    const float* x = (const float*)d_in[0];
    const float* m = (const float*)d_in[1];
    float* out = (float*)d_out;
    float* hbuf = (float*)d_ws;

    const double sr = 40.0, q = 0.7071067811865476;
    // highpass fc = 0.5
    double w0h = 2.0 * M_PI * 0.5 / sr;
    double alh = sin(w0h) / (2.0 * q), cwh = cos(w0h), a0h = 1.0 + alh;
    double b0h = ((1.0 + cwh) * 0.5) / a0h, b1h = (-(1.0 + cwh)) / a0h, b2h = b0h;
    double a1h = (-2.0 * cwh) / a0h,       a2h = (1.0 - alh) / a0h;
    // lowpass fc = 50
    double w0l = 2.0 * M_PI * 50.0 / sr;
    double all = sin(w0l) / (2.0 * q), cwl = cos(w0l), a0l = 1.0 + all;
    double b0l = ((1.0 - cwl) * 0.5) / a0l, b1l = (1.0 - cwl) / a0l, b2l = b0l;
    double a1l = (-2.0 * cwl) / a0l,        a2l = (1.0 - all) / a0l;

    make_h<<<1, 64, 0, stream>>>(hbuf, b0h, b1h, b2h, a1h, a2h,
                                        b0l, b1l, b2l, a1l, a2l);

    int grid = BB * NCHUNK;   // 8192 blocks: (batch, 256-sample chunk)
    collate_fir<<<grid, 256, 0, stream>>>(x, m, out, hbuf);
}

// Round 9
// 200.731 us; speedup vs baseline: 1.8763x; 1.8763x over previous
//
#include <hip/hip_runtime.h>
#include <math.h>

#ifndef M_PI
#define M_PI 3.14159265358979323846
#endif

#define BB     128
#define TT     16384
#define PP     20
#define NCH    18
#define EMIT   256                 // emitted samples per block
#define HIST   192                 // FIR history (0.946^192 ~ 2e-5)
#define WIN    (HIST + EMIT)       // 448 converted rows per block
#define NQ     7                   // K-chunks of 32
#define NTAPS  208                 // h[0..207]
#define VPITCH 488                 // v row pitch in u16 (%8==0 for b128 align, >=464)
#define NCHUNK (TT / EMIT)         // 64

typedef float  f32x4v __attribute__((ext_vector_type(4)));
typedef short  bf16x8 __attribute__((ext_vector_type(8)));

__device__ __forceinline__ uint rne16(float f) {
    uint u = __float_as_uint(f);
    return (u + 0x7fffu + ((u >> 16) & 1u)) >> 16;   // round-nearest-even bf16 bits
}

// 1-thread pre-kernel: h = impulse response of HP->LP cascade, double DF1
__global__ void make_h(float* __restrict__ hout,
                       double b0h, double b1h, double b2h, double a1h, double a2h,
                       double b0l, double b1l, double b2l, double a1l, double a2l)
{
    if (threadIdx.x == 0 && blockIdx.x == 0) {
        double hx1=0, hx2=0, hy1=0, hy2=0, lx1=0, lx2=0, ly1=0, ly2=0;
        for (int t = 0; t < NTAPS; ++t) {
            double u = (t == 0) ? 1.0 : 0.0;
            double hy = b0h*u + b1h*hx1 + b2h*hx2 - a1h*hy1 - a2h*hy2;
            hx2 = hx1; hx1 = u;  hy2 = hy1; hy1 = hy;
            double ly = b0l*hy + b1l*lx1 + b2l*lx2 - a1l*ly1 - a2l*ly2;
            lx2 = lx1; lx1 = hy; ly2 = ly1; ly1 = ly;
            hout[t] = (float)ly;
        }
    }
}

__global__ __launch_bounds__(256, 4) void collate_fir(
    const float* __restrict__ x, const float* __restrict__ msk,
    float* __restrict__ out, const float* __restrict__ hg)
{
    __shared__ ushort vhi[NCH * VPITCH];   // 17568 B
    __shared__ ushort vlo[NCH * VPITCH];   // 17568 B   (total 35136 -> 4 blocks/CU)

    int tid   = threadIdx.x;
    int blk   = blockIdx.x;
    int chunk = blk & (NCHUNK - 1);
    int b     = blk >> 6;
    int t0    = chunk * EMIT;

    // ---- zero v slack [WIN, VPITCH) (read by main tile 15 as h-zero region)
    for (int e = tid; e < NCH * (VPITCH - WIN); e += 256) {
        int c = e / (VPITCH - WIN);
        int w = WIN + (e - c * (VPITCH - WIN));
        vhi[c * VPITCH + w] = 0;
        vlo[c * VPITCH + w] = 0;
    }

    const float* xb   = x   + (size_t)b * TT * PP;
    const float* mb   = msk + (size_t)b * TT * PP;
    float*       oute = out;
    float*       outm = out + (size_t)BB * NCH * TT;

    // ---- conversion: one time-row per thread, straight from global -------
    constexpr int P1[NCH] = {0,4,5,6,  0,1,2,3,  11,15,16,17, 11,12,13,14, 8,9};
    constexpr int P2[NCH] = {4,5,6,7,  1,2,3,7,  15,16,17,18, 12,13,14,18, 9,10};

    for (int r = tid; r < WIN; r += 256) {
        int trow = t0 - HIST + r;            // may be negative for chunk 0
        float xr[PP], mr[PP];
        if (trow >= 0) {
            const f32x4v* xp = reinterpret_cast<const f32x4v*>(xb + (size_t)trow * PP);
            const f32x4v* mp = reinterpret_cast<const f32x4v*>(mb + (size_t)trow * PP);
#pragma unroll
            for (int j = 0; j < 5; ++j) {
                f32x4v a = xp[j], mm = mp[j];
                xr[4*j+0] = a.x;  xr[4*j+1] = a.y;  xr[4*j+2] = a.z;  xr[4*j+3] = a.w;
                mr[4*j+0] = mm.x; mr[4*j+1] = mm.y; mr[4*j+2] = mm.z; mr[4*j+3] = mm.w;
            }
        } else {
#pragma unroll
            for (int j = 0; j < PP; ++j) { xr[j] = 0.f; mr[j] = 0.f; }
        }
        bool emitpm = (r >= HIST);
        size_t pmoff = ((size_t)b * NCH) * TT + (size_t)t0 + (r - HIST);
#pragma unroll
        for (int c = 0; c < NCH; ++c) {
            float pm = mr[P1[c]] * mr[P2[c]];
            float v  = (xr[P1[c]] - xr[P2[c]]) * pm;
            uint vh  = rne16(v);
            uint vl  = rne16(v - __uint_as_float(vh << 16));
            vhi[c * VPITCH + r] = (ushort)vh;
            vlo[c * VPITCH + r] = (ushort)vl;
            if (emitpm) outm[pmoff + (size_t)c * TT] = pm;   // 256B/wave contiguous
        }
    }

    // ---- A fragments: Toeplitz h slices, hi/lo bf16 (global h, L1-hot) ----
    int lane = tid & 63;
    int wid  = tid >> 6;
    int i16  = lane & 15;
    int g    = lane >> 4;

    bf16x8 Ah[NQ], Al[NQ];
#pragma unroll
    for (int q = 0; q < NQ; ++q) {
#pragma unroll
        for (int e = 0; e < 8; ++e) {
            int   k  = i16 + HIST - 32 * q - (g * 8 + e);
            float hv = (k >= 0 && k < NTAPS) ? hg[k] : 0.f;
            uint  hh = rne16(hv);
            uint  hl = rne16(hv - __uint_as_float(hh << 16));
            Ah[q][e] = (short)hh;
            Al[q][e] = (short)hl;
        }
    }

    __syncthreads();

    // ---- MFMA: 16 main tiles (c=0..15) + 2 packed tiles (c=16,17 x 8 sub) -
    for (int tile = wid; tile < 18; tile += 4) {
        int n = lane & 15;
        int c, Tl;
        if (tile < 16) { c = n;             Tl = tile * 16; }
        else           { c = 16 + (n >> 3); Tl = (tile - 16) * 128 + (n & 7) * 16; }

        f32x4v acc = {0.f, 0.f, 0.f, 0.f};
#pragma unroll
        for (int q = 0; q < NQ; ++q) {
            int off = c * VPITCH + Tl + 32 * q + 8 * g;
            bf16x8 Bh = *reinterpret_cast<bf16x8*>(&vhi[off]);
            bf16x8 Bl = *reinterpret_cast<bf16x8*>(&vlo[off]);
            acc = __builtin_amdgcn_mfma_f32_16x16x32_bf16(Ah[q], Bh, acc, 0, 0, 0);
            acc = __builtin_amdgcn_mfma_f32_16x16x32_bf16(Ah[q], Bl, acc, 0, 0, 0);
            acc = __builtin_amdgcn_mfma_f32_16x16x32_bf16(Al[q], Bh, acc, 0, 0, 0);
        }
        // C/D: col = lane&15, row = g*4 + reg -> 4 consecutive output times
        *reinterpret_cast<f32x4v*>(oute + ((size_t)b * NCH + c) * TT + t0 + Tl + g * 4) = acc;
    }
}

extern "C" void kernel_launch(void* const* d_in, const int* in_sizes, int n_in,
                              void* d_out, int out_size, void* d_ws, size_t ws_size,
                              hipStream_t stream)
{
    const float* x = (const float*)d_in[0];
    const float* m = (const float*)d_in[1];
    float* out = (float*)d_out;
    float* hbuf = (float*)d_ws;

    const double sr = 40.0, q = 0.7071067811865476;
    // highpass fc = 0.5
    double w0h = 2.0 * M_PI * 0.5 / sr;
    double alh = sin(w0h) / (2.0 * q), cwh = cos(w0h), a0h = 1.0 + alh;
    double b0h = ((1.0 + cwh) * 0.5) / a0h, b1h = (-(1.0 + cwh)) / a0h, b2h = b0h;
    double a1h = (-2.0 * cwh) / a0h,       a2h = (1.0 - alh) / a0h;
    // lowpass fc = 50
    double w0l = 2.0 * M_PI * 50.0 / sr;
    double all = sin(w0l) / (2.0 * q), cwl = cos(w0l), a0l = 1.0 + all;
    double b0l = ((1.0 - cwl) * 0.5) / a0l, b1l = (1.0 - cwl) / a0l, b2l = b0l;
    double a1l = (-2.0 * cwl) / a0l,        a2l = (1.0 - all) / a0l;

    make_h<<<1, 64, 0, stream>>>(hbuf, b0h, b1h, b2h, a1h, a2h,
                                        b0l, b1l, b2l, a1l, a2l);

    int grid = BB * NCHUNK;   // 8192 blocks: (batch, 256-sample chunk)
    collate_fir<<<grid, 256, 0, stream>>>(x, m, out, hbuf);
}